// Round 1
// baseline (175.410 us; speedup 1.0000x reference)
//
#include <hip/hip_runtime.h>
#include <hip/hip_bf16.h>

// DisenGCN forward on MI355X.
// Sides: 0 = user (eu), 1 = item (ei). N_ROWS = n_neigh + 1 = 4097.
// Layer geometry: d_in=64, K=4 channels, d_out=16, flat out = 64.
//
// ws layout (floats):
//   zU  : N_ROWS*64   raw projection outputs, side U (reused across layers, in-place L1)
//   zI  : N_ROWS*64   side I
//   acc : 12*64       routed row-0 results, slot(L,t,side) = ((L*3+t)*2+side)*64

#define ROWS_PER_BLOCK 4
#define ROUTE_BLOCKS 32

__global__ void zero_acc_kernel(float* __restrict__ acc) {
    for (int i = threadIdx.x; i < 12 * 64; i += blockDim.x) acc[i] = 0.f;
}

// One wave (64 lanes) per row. Lane m computes output element m = k*16+d:
//   z[n][m] = relu(b[k][d] + sum_i x[i] * W[k][i][d])
__global__ void proj_kernel(
    const float* __restrict__ Gu, const float* __restrict__ Gi,
    const int* __restrict__ user, const int* __restrict__ item,
    const int* __restrict__ neigh_user, const int* __restrict__ neigh_item,
    const float* __restrict__ W, const float* __restrict__ b,
    float* __restrict__ zU, float* __restrict__ zI,
    const float* __restrict__ accPrev,  // layer-1: routed row-0 inputs (base, +side*64); null for layer 0
    int layer, int n_rows)
{
    const int lane = threadIdx.x & 63;
    const int wave = threadIdx.x >> 6;
    const int n = blockIdx.x * ROWS_PER_BLOCK + wave;
    if (n >= n_rows) return;
    const int side = blockIdx.y;
    float* __restrict__ zbuf = side ? zI : zU;

    float x;
    if (layer == 0) {
        if (n == 0) {
            x = side ? Gi[(size_t)item[0] * 64 + lane]
                     : Gu[(size_t)user[0] * 64 + lane];
        } else {
            x = side ? Gu[(size_t)neigh_item[n - 1] * 64 + lane]
                     : Gi[(size_t)neigh_user[n - 1] * 64 + lane];
        }
    } else {
        x = (n == 0) ? accPrev[side * 64 + lane] : zbuf[(size_t)n * 64 + lane];
    }

    const int k = lane >> 4, d = lane & 15;
    float sum = b[k * 16 + d];
    const float* __restrict__ Wp = W + (size_t)(k * 64) * 16 + d;  // W[k][i][d], stride 16 over i
#pragma unroll
    for (int i = 0; i < 64; ++i) {
        float xi = __shfl(x, i, 64);
        sum = fmaf(xi, Wp[i * 16], sum);
    }
    zbuf[(size_t)n * 64 + lane] = fmaxf(sum, 0.f);
}

// One routing iteration, both sides (blockIdx.y). Rows normalized on the fly.
// ego source: z row 0 (t==0) or previous iteration's acc slot.
// Result accumulated via atomicAdd into pre-zeroed acc_out (+side*64).
__global__ void route_kernel(
    const float* __restrict__ zU, const float* __restrict__ zI,
    const float* __restrict__ ego_src,  // acc slot base (+side*64) when use_z_row0==0
    float* __restrict__ acc_out,        // +side*64
    int use_z_row0, int n_neigh)
{
    const int lane = threadIdx.x & 63;
    const int wave = threadIdx.x >> 6;
    const int side = blockIdx.y;
    const float* __restrict__ zbuf = side ? zI : zU;

    // normalized ego (redundant per wave; 64 floats)
    float e = use_z_row0 ? zbuf[lane] : ego_src[side * 64 + lane];
    float ss = e * e;
    ss += __shfl_xor(ss, 1, 64); ss += __shfl_xor(ss, 2, 64);
    ss += __shfl_xor(ss, 4, 64); ss += __shfl_xor(ss, 8, 64);
    const float egon = e / fmaxf(sqrtf(ss), 1e-12f);

    float accLocal = 0.f;
    const int nwaves = gridDim.x * (blockDim.x >> 6);
    const int wid = blockIdx.x * (blockDim.x >> 6) + wave;
    for (int n = 1 + wid; n <= n_neigh; n += nwaves) {
        float zv = zbuf[(size_t)n * 64 + lane];
        float s2 = zv * zv;
        s2 += __shfl_xor(s2, 1, 64); s2 += __shfl_xor(s2, 2, 64);
        s2 += __shfl_xor(s2, 4, 64); s2 += __shfl_xor(s2, 8, 64);
        float znv = zv / fmaxf(sqrtf(s2), 1e-12f);
        float dp = znv * egon;
        dp += __shfl_xor(dp, 1, 64); dp += __shfl_xor(dp, 2, 64);
        dp += __shfl_xor(dp, 4, 64); dp += __shfl_xor(dp, 8, 64);
        // dp = dot for my k-group (uniform within each 16-lane group)
        float d0 = __shfl(dp, 0, 64),  d1 = __shfl(dp, 16, 64);
        float d2 = __shfl(dp, 32, 64), d3 = __shfl(dp, 48, 64);
        float mx = fmaxf(fmaxf(d0, d1), fmaxf(d2, d3));
        float denom = expf(d0 - mx) + expf(d1 - mx) + expf(d2 - mx) + expf(d3 - mx);
        float pk = expf(dp - mx) / denom;
        accLocal = fmaf(pk, znv, accLocal);
    }

    __shared__ float red[4][64];
    red[wave][lane] = accLocal;
    __syncthreads();
    if (wave == 0) {
        float s = red[0][lane] + red[1][lane] + red[2][lane] + red[3][lane];
        atomicAdd(&acc_out[side * 64 + lane], s);
    }
}

__global__ void final_kernel(const float* __restrict__ acc, float* __restrict__ out) {
    const int lane = threadIdx.x;  // 64 threads
    float u = acc[10 * 64 + lane];
    float v = acc[11 * 64 + lane];
    out[1 + lane] = u;
    out[65 + lane] = v;
    float p = u * v;
    for (int s = 32; s >= 1; s >>= 1) p += __shfl_xor(p, s, 64);
    if (lane == 0) out[0] = p;
}

extern "C" void kernel_launch(void* const* d_in, const int* in_sizes, int n_in,
                              void* d_out, int out_size, void* d_ws, size_t ws_size,
                              hipStream_t stream) {
    const int*   user       = (const int*)d_in[0];
    const int*   item       = (const int*)d_in[1];
    const int*   neigh_user = (const int*)d_in[2];
    const int*   neigh_item = (const int*)d_in[3];
    const float* Gu         = (const float*)d_in[4];
    const float* Gi         = (const float*)d_in[5];
    const float* W0         = (const float*)d_in[6];
    const float* b0         = (const float*)d_in[7];
    const float* W1         = (const float*)d_in[8];
    const float* b1         = (const float*)d_in[9];
    float* out = (float*)d_out;

    const int n_neigh = in_sizes[2];
    const int n_rows  = n_neigh + 1;

    float* zU  = (float*)d_ws;
    float* zI  = zU + (size_t)n_rows * 64;
    float* acc = zI + (size_t)n_rows * 64;

    hipLaunchKernelGGL(zero_acc_kernel, dim3(1), dim3(256), 0, stream, acc);

    const dim3 pgrid((n_rows + ROWS_PER_BLOCK - 1) / ROWS_PER_BLOCK, 2);
    const dim3 pblock(64 * ROWS_PER_BLOCK);
    const dim3 rgrid(ROUTE_BLOCKS, 2);

    // ---- layer 0 ----
    hipLaunchKernelGGL(proj_kernel, pgrid, pblock, 0, stream,
                       Gu, Gi, user, item, neigh_user, neigh_item, W0, b0,
                       zU, zI, (const float*)nullptr, 0, n_rows);
    for (int t = 0; t < 3; ++t) {
        const float* ein = acc + (size_t)((t - 1) * 2) * 64;  // valid only when t>0
        float* eout = acc + (size_t)(t * 2) * 64;
        hipLaunchKernelGGL(route_kernel, rgrid, dim3(256), 0, stream,
                           zU, zI, ein, eout, (t == 0) ? 1 : 0, n_neigh);
    }
    // ---- layer 1 (in-place over z, row 0 from slot(0,2)) ----
    hipLaunchKernelGGL(proj_kernel, pgrid, pblock, 0, stream,
                       Gu, Gi, user, item, neigh_user, neigh_item, W1, b1,
                       zU, zI, acc + (size_t)(2 * 2) * 64, 1, n_rows);
    for (int t = 0; t < 3; ++t) {
        const float* ein = acc + (size_t)((3 + t - 1) * 2) * 64;
        float* eout = acc + (size_t)((3 + t) * 2) * 64;
        hipLaunchKernelGGL(route_kernel, rgrid, dim3(256), 0, stream,
                           zU, zI, ein, eout, (t == 0) ? 1 : 0, n_neigh);
    }

    hipLaunchKernelGGL(final_kernel, dim3(1), dim3(64), 0, stream, acc, out);
}